// Round 4
// baseline (1575.582 us; speedup 1.0000x reference)
//
#include <hip/hip_runtime.h>

#define FIN 128
#define HID 32
#define BSHIFT 6                 // 64 nodes per bucket
#define BNODES 64
#define P2_CHUNK 32768           // edges per block in bucket-scatter kernel

// ---------------- P2: bucket-scatter edges ----------------
// entries[b*cap + i] = src | (dlocal << 25), grouped by coarse bucket b = dst>>6.
// Per-block LDS histogram + ONE aggregated global atomic per (block,bucket).

__global__ __launch_bounds__(256) void bucket_scatter_kernel(const int* __restrict__ src,
                                                             const int* __restrict__ dst,
                                                             int* __restrict__ fill,
                                                             int* __restrict__ entries,
                                                             int E, int nb, int cap) {
    extern __shared__ int hist[];   // nb ints
    int t = threadIdx.x;
    for (int i = t; i < nb; i += 256) hist[i] = 0;
    __syncthreads();
    int beg = blockIdx.x * P2_CHUNK;
    int end = min(beg + P2_CHUNK, E);
    for (int i = beg + t; i < end; i += 256) {
        int b = ((unsigned)dst[i]) >> BSHIFT;
        atomicAdd(&hist[b], 1);
    }
    __syncthreads();
    // claim contiguous range in each bucket; hist becomes the running cursor
    for (int b = t; b < nb; b += 256) {
        int c = hist[b];
        hist[b] = (c > 0) ? atomicAdd(&fill[b], c) : 0;
    }
    __syncthreads();
    for (int i = beg + t; i < end; i += 256) {
        int d = dst[i];
        int b = ((unsigned)d) >> BSHIFT;
        int pos = atomicAdd(&hist[b], 1);
        if (pos < cap)
            entries[(size_t)b * cap + pos] = src[i] | ((d & (BNODES - 1)) << 25);
    }
}

// ---------------- dinv from bucket entries ----------------

__global__ __launch_bounds__(256) void bucket_dinv_kernel(const int* __restrict__ entries,
                                                          const int* __restrict__ fill,
                                                          float* __restrict__ dinv,
                                                          int n, int cap) {
    __shared__ int degl[BNODES];
    int b = blockIdx.x, t = threadIdx.x;
    if (t < BNODES) degl[t] = 0;
    __syncthreads();
    int cnt = min(fill[b], cap);
    const int* ep = entries + (size_t)b * cap;
    for (int i = t; i < cnt; i += 256) {
        int dl = ((unsigned)ep[i]) >> 25;
        atomicAdd(&degl[dl], 1);
    }
    __syncthreads();
    int node = b * BNODES + t;
    if (t < BNODES && node < n)
        dinv[node] = rsqrtf((float)degl[t] + 1.0f);   // +1 = self-loop
}

// ---------------- weight fill: w[e] = dinv[src]*dinv[dst] ----------------

__global__ __launch_bounds__(256) void wfill_kernel(const int* __restrict__ entries,
                                                    const int* __restrict__ fill,
                                                    const float* __restrict__ dinv,
                                                    float* __restrict__ wts,
                                                    int n, int cap) {
    __shared__ float dloc[BNODES];
    int b = blockIdx.x, t = threadIdx.x;
    int node0 = b * BNODES;
    if (t < BNODES) dloc[t] = (node0 + t < n) ? dinv[node0 + t] : 0.f;
    __syncthreads();
    int cnt = min(fill[b], cap);
    const int* ep = entries + (size_t)b * cap;
    float* wp = wts + (size_t)b * cap;
    #pragma unroll 4
    for (int i = t; i < cnt; i += 256) {
        int e = ep[i];
        int s = e & 0x1FFFFFF;
        int dl = ((unsigned)e) >> 25;
        wp[i] = dinv[s] * dloc[dl];
    }
}

// ---------------- GEMM1: h0 = x @ W1  [n,128]@[128,32] ----------------

__global__ __launch_bounds__(256) void gemm1_kernel(const float* __restrict__ x,
                                                    const float* __restrict__ W,
                                                    float* __restrict__ h0, int n) {
    __shared__ float Ws[FIN * HID];   // 16 KB
    __shared__ float xs[8][FIN];      // 4 KB
    int t = threadIdx.x;
    for (int i = t; i < FIN * HID; i += 256) Ws[i] = W[i];
    int row0 = blockIdx.x * 8;
    {
        int r  = t >> 5;
        int c4 = (t & 31) * 4;
        int row = row0 + r;
        float4 v = (row < n) ? *(const float4*)&x[(size_t)row * FIN + c4]
                             : make_float4(0.f, 0.f, 0.f, 0.f);
        *(float4*)&xs[r][c4] = v;
    }
    __syncthreads();
    int r = t >> 5, col = t & 31;
    int row = row0 + r;
    if (row < n) {
        float acc = 0.f;
        #pragma unroll 16
        for (int k = 0; k < FIN; ++k) acc += xs[r][k] * Ws[k * HID + col];
        h0[(size_t)row * HID + col] = acc;
    }
}

// ---------------- AGG: per-bucket LDS accumulation, 8-deep MLP ----------------
// out[i] = relu?( bias + h[i]*dinv[i]^2 + sum_{e: dst=i} h[src]*w_e )

__global__ __launch_bounds__(256) void agg_kernel(const int* __restrict__ entries,
                                                  const float* __restrict__ wts,
                                                  const int* __restrict__ fill,
                                                  const float* __restrict__ dinv,
                                                  const float* __restrict__ h,
                                                  const float* __restrict__ bias,
                                                  float* __restrict__ out,
                                                  int n, int cap, int relu) {
    __shared__ float accs[BNODES][HID];   // 8 KB
    int b = blockIdx.x, t = threadIdx.x;
    int node0 = b * BNODES;
    int nnodes = min(BNODES, n - node0);
    int g = t >> 5, f = t & 31;           // 8 groups of 32 lanes
    // init: bias + self-loop term
    for (int r = g; r < nnodes; r += 8) {
        float di = dinv[node0 + r];
        accs[r][f] = bias[f] + h[(size_t)(node0 + r) * HID + f] * di * di;
    }
    __syncthreads();
    int cnt = min(fill[b], cap);
    const int* ep = entries + (size_t)b * cap;
    const float* wp = wts + (size_t)b * cap;
    // each group takes 32-edge slabs, strided by 256 across the block
    for (int base = g * 32; base < cnt; base += 256) {
        int idx = base + f;
        bool valid = idx < cnt;
        int   sv = valid ? ep[idx] : 0;
        float wv = valid ? wp[idx] : 0.f;   // w=0 => dummy edge adds 0 to accs[0][f]
        #pragma unroll
        for (int j0 = 0; j0 < 32; j0 += 8) {
            float v[8], ww[8];
            int   dl[8];
            #pragma unroll
            for (int j = 0; j < 8; ++j) {
                int e  = __shfl(sv, j0 + j, 32);
                ww[j]  = __shfl(wv, j0 + j, 32);
                int s  = e & 0x1FFFFFF;
                dl[j]  = ((unsigned)e) >> 25;
                v[j]   = h[(size_t)s * HID + f];   // 8 loads in flight
            }
            #pragma unroll
            for (int j = 0; j < 8; ++j)
                atomicAdd(&accs[dl[j]][f], v[j] * ww[j]);
        }
    }
    __syncthreads();
    for (int r = g; r < nnodes; r += 8) {
        float v = accs[r][f];
        if (relu) v = fmaxf(v, 0.f);
        out[(size_t)(node0 + r) * HID + f] = v;
    }
}

// ---------------- GEMM2: h2 = h @ W2  [n,32]@[32,32] (input already relu'ed) ----------------

__global__ __launch_bounds__(256) void gemm2_kernel(const float* __restrict__ hin,
                                                    const float* __restrict__ W,
                                                    float* __restrict__ h2, int n) {
    __shared__ float Ws[HID * HID];
    __shared__ float hs[8][HID];
    int t = threadIdx.x;
    for (int i = t; i < HID * HID; i += 256) Ws[i] = W[i];
    int row0 = blockIdx.x * 8;
    {
        int r = t >> 5, c = t & 31;
        int row = row0 + r;
        hs[r][c] = (row < n) ? hin[(size_t)row * HID + c] : 0.f;
    }
    __syncthreads();
    int r = t >> 5, col = t & 31;
    int row = row0 + r;
    if (row < n) {
        float s = 0.f;
        #pragma unroll
        for (int k = 0; k < HID; ++k) s += hs[r][k] * Ws[k * HID + col];
        h2[(size_t)row * HID + col] = s;
    }
}

extern "C" void kernel_launch(void* const* d_in, const int* in_sizes, int n_in,
                              void* d_out, int out_size, void* d_ws, size_t ws_size,
                              hipStream_t stream) {
    const float* x  = (const float*)d_in[0];
    const int*   ei = (const int*)d_in[1];
    const float* W1 = (const float*)d_in[2];
    const float* b1 = (const float*)d_in[3];
    const float* W2 = (const float*)d_in[4];
    const float* b2 = (const float*)d_in[5];
    float* out = (float*)d_out;

    int n = in_sizes[0] / FIN;      // 100000
    int E = in_sizes[1] / 2;        // 3200000
    const int* src = ei;
    const int* dst = ei + E;

    int nb = (n + BNODES - 1) / BNODES;          // 1563 buckets

    // bucket capacity: mean E/nb ≈ 2048, max over 1563 buckets ≈ 2250 (Poisson).
    // entries + wts cost 8 B per slot; shrink cap if workspace is tight.
    size_t fixed = (size_t)nb * 4 + (size_t)n * 4 + 2 * (size_t)n * HID * 4 + 8192;
    int cap = 2560;
    if (ws_size) {
        size_t avail = (ws_size > fixed) ? (ws_size - fixed) : 0;
        int maxcap = (int)(avail / ((size_t)nb * 8));
        if (maxcap < cap) cap = maxcap & ~31;
    }

    char* ws = (char*)d_ws;
    size_t off = 0;
    auto alloc = [&](size_t bytes) { char* p = ws + off; off += (bytes + 255) & ~(size_t)255; return p; };
    int*   entries = (int*)alloc((size_t)nb * cap * 4);
    float* wts     = (float*)alloc((size_t)nb * cap * 4);
    int*   fill    = (int*)alloc((size_t)nb * 4);
    float* dinv    = (float*)alloc((size_t)n * 4);
    float* h0      = (float*)alloc((size_t)n * HID * 4);
    float* acc     = (float*)alloc((size_t)n * HID * 4);
    float* h2      = h0;   // h0 dead after agg1

    // ---- preprocessing: bucket sort + dinv + edge weights ----
    hipMemsetAsync(fill, 0, (size_t)nb * 4, stream);
    {
        int nblocks = (E + P2_CHUNK - 1) / P2_CHUNK;
        bucket_scatter_kernel<<<nblocks, 256, nb * 4, stream>>>(src, dst, fill, entries, E, nb, cap);
    }
    bucket_dinv_kernel<<<nb, 256, 0, stream>>>(entries, fill, dinv, n, cap);
    wfill_kernel<<<nb, 256, 0, stream>>>(entries, fill, dinv, wts, n, cap);

    // ---- layer 1 ----
    gemm1_kernel<<<(n + 7) / 8, 256, 0, stream>>>(x, W1, h0, n);
    agg_kernel<<<nb, 256, 0, stream>>>(entries, wts, fill, dinv, h0, b1, acc, n, cap, 1);

    // ---- layer 2 ----
    gemm2_kernel<<<(n + 7) / 8, 256, 0, stream>>>(acc, W2, h2, n);
    agg_kernel<<<nb, 256, 0, stream>>>(entries, wts, fill, dinv, h2, b2, out, n, cap, 1);
}

// Round 5
// 439.230 us; speedup vs baseline: 3.5871x; 3.5871x over previous
//
#include <hip/hip_runtime.h>
#include <hip/hip_fp16.h>

#define FIN 128
#define HID 32
#define BSHIFT 6                 // 64 nodes per bucket
#define BNODES 64
#define P2_CHUNK 32768           // edges per block in bucket-scatter kernel
#define CAPMAX 2560              // max entries per bucket (mean 2047, max ~2200)

// ---------------- P2: bucket-scatter edges ----------------
// entries[b*cap + i] = src | (dlocal << 25), grouped by coarse bucket b = dst>>6.

__global__ __launch_bounds__(256) void bucket_scatter_kernel(const int* __restrict__ src,
                                                             const int* __restrict__ dst,
                                                             int* __restrict__ fill,
                                                             int* __restrict__ entries,
                                                             int E, int nb, int cap) {
    extern __shared__ int hist[];   // nb ints
    int t = threadIdx.x;
    for (int i = t; i < nb; i += 256) hist[i] = 0;
    __syncthreads();
    int beg = blockIdx.x * P2_CHUNK;
    int end = min(beg + P2_CHUNK, E);
    for (int i = beg + t; i < end; i += 256) {
        int b = ((unsigned)dst[i]) >> BSHIFT;
        atomicAdd(&hist[b], 1);
    }
    __syncthreads();
    for (int b = t; b < nb; b += 256) {
        int c = hist[b];
        hist[b] = (c > 0) ? atomicAdd(&fill[b], c) : 0;
    }
    __syncthreads();
    for (int i = beg + t; i < end; i += 256) {
        int d = dst[i];
        int b = ((unsigned)d) >> BSHIFT;
        int pos = atomicAdd(&hist[b], 1);
        if (pos < cap)
            entries[(size_t)b * cap + pos] = src[i] | ((d & (BNODES - 1)) << 25);
    }
}

// ---------------- counting sort within each bucket (LDS) + dinv + rowptr ----------------

__global__ __launch_bounds__(256) void bucket_sortdinv_kernel(int* __restrict__ entries,
                                                              const int* __restrict__ fill,
                                                              float* __restrict__ dinv,
                                                              int* __restrict__ rowbeg,
                                                              int* __restrict__ rowcnt,
                                                              int n, int cap) {
    __shared__ int raw[CAPMAX];
    __shared__ int srt[CAPMAX];
    __shared__ int hist[BNODES];
    __shared__ int pref[BNODES];
    __shared__ int cursor[BNODES];
    int b = blockIdx.x, t = threadIdx.x;
    int base = b * cap;
    int cnt = min(fill[b], cap);
    int* ep = entries + (size_t)base;
    if (t < BNODES) hist[t] = 0;
    __syncthreads();
    for (int i = t; i < cnt; i += 256) {
        int e = ep[i];
        raw[i] = e;
        atomicAdd(&hist[((unsigned)e) >> 25], 1);
    }
    __syncthreads();
    if (t == 0) {                      // tiny serial scan over 64 counters
        int run = 0;
        for (int i = 0; i < BNODES; ++i) { pref[i] = run; run += hist[i]; }
    }
    __syncthreads();
    if (t < BNODES) cursor[t] = pref[t];
    __syncthreads();
    for (int i = t; i < cnt; i += 256) {
        int e = raw[i];
        int dl = ((unsigned)e) >> 25;
        int p = atomicAdd(&cursor[dl], 1);
        srt[p] = e;
    }
    __syncthreads();
    for (int i = t; i < cnt; i += 256) ep[i] = srt[i];  // coalesced write-back, now node-sorted
    int node = b * BNODES + t;
    if (t < BNODES && node < n) {
        int deg = hist[t];
        dinv[node]   = rsqrtf((float)deg + 1.0f);   // +1 = self-loop
        rowbeg[node] = base + pref[t];
        rowcnt[node] = deg;
    }
}

// ---------------- weight fill: w[e] = dinv[src]*dinv[dst] ----------------

__global__ __launch_bounds__(256) void wfill_kernel(const int* __restrict__ entries,
                                                    const int* __restrict__ fill,
                                                    const float* __restrict__ dinv,
                                                    float* __restrict__ wts,
                                                    int n, int cap) {
    __shared__ float dloc[BNODES];
    int b = blockIdx.x, t = threadIdx.x;
    int node0 = b * BNODES;
    if (t < BNODES) dloc[t] = (node0 + t < n) ? dinv[node0 + t] : 0.f;
    __syncthreads();
    int cnt = min(fill[b], cap);
    const int* ep = entries + (size_t)b * cap;
    float* wp = wts + (size_t)b * cap;
    #pragma unroll 4
    for (int i = t; i < cnt; i += 256) {
        int e = ep[i];
        int s = e & 0x1FFFFFF;
        int dl = ((unsigned)e) >> 25;
        wp[i] = dinv[s] * dloc[dl];
    }
}

// ---------------- GEMM1: h0 = x @ W1, dual-store fp32 + fp16 ----------------

__global__ __launch_bounds__(256) void gemm1_kernel(const float* __restrict__ x,
                                                    const float* __restrict__ W,
                                                    float* __restrict__ h0,
                                                    __half* __restrict__ h0h, int n) {
    __shared__ float Ws[FIN * HID];   // 16 KB
    __shared__ float xs[8][FIN];      // 4 KB
    int t = threadIdx.x;
    for (int i = t; i < FIN * HID; i += 256) Ws[i] = W[i];
    int row0 = blockIdx.x * 8;
    {
        int r  = t >> 5;
        int c4 = (t & 31) * 4;
        int row = row0 + r;
        float4 v = (row < n) ? *(const float4*)&x[(size_t)row * FIN + c4]
                             : make_float4(0.f, 0.f, 0.f, 0.f);
        *(float4*)&xs[r][c4] = v;
    }
    __syncthreads();
    int r = t >> 5, col = t & 31;
    int row = row0 + r;
    if (row < n) {
        float acc = 0.f;
        #pragma unroll 16
        for (int k = 0; k < FIN; ++k) acc += xs[r][k] * Ws[k * HID + col];
        h0[(size_t)row * HID + col]  = acc;
        h0h[(size_t)row * HID + col] = __float2half(acc);
    }
}

// ---------------- gather: per-node register accumulation, fp16 neighbor rows ----------------
// out[i] = relu?( bias + h32[i]*dinv[i]^2 + sum_e h16[src]*w_e )

__global__ __launch_bounds__(256) void gather_kernel(const int* __restrict__ entries,
                                                     const float* __restrict__ wts,
                                                     const int* __restrict__ rowbeg,
                                                     const int* __restrict__ rowcnt,
                                                     const float* __restrict__ dinv,
                                                     const float* __restrict__ h32,
                                                     const __half* __restrict__ h16,
                                                     const float* __restrict__ bias,
                                                     float* __restrict__ out, int n, int relu) {
    int g = threadIdx.x >> 5, f = threadIdx.x & 31;
    int i = blockIdx.x * 8 + g;
    if (i >= n) return;
    float di = dinv[i];
    float acc = bias[f] + h32[(size_t)i * HID + f] * di * di;
    int beg = rowbeg[i], cnt = rowcnt[i];
    for (int base = 0; base < cnt; base += 32) {
        int idx = beg + base + f;
        bool valid = (base + f) < cnt;
        int   sv = valid ? entries[idx] : 0;
        float wv = valid ? wts[idx] : 0.f;      // w=0 => dummy edge contributes 0
        #pragma unroll
        for (int j0 = 0; j0 < 32; j0 += 8) {
            float hv[8], ww[8];
            #pragma unroll
            for (int j = 0; j < 8; ++j) {
                int e = __shfl(sv, j0 + j, 32);
                ww[j] = __shfl(wv, j0 + j, 32);
                hv[j] = __half2float(h16[(size_t)(e & 0x1FFFFFF) * HID + f]);
            }
            #pragma unroll
            for (int j = 0; j < 8; ++j) acc = fmaf(hv[j], ww[j], acc);
        }
    }
    if (relu) acc = fmaxf(acc, 0.f);
    out[(size_t)i * HID + f] = acc;
}

// ---------------- GEMM2: h2 = hin @ W2, dual-store fp32 + fp16 ----------------

__global__ __launch_bounds__(256) void gemm2_kernel(const float* __restrict__ hin,
                                                    const float* __restrict__ W,
                                                    float* __restrict__ h2,
                                                    __half* __restrict__ h2h, int n) {
    __shared__ float Ws[HID * HID];
    __shared__ float hs[8][HID];
    int t = threadIdx.x;
    for (int i = t; i < HID * HID; i += 256) Ws[i] = W[i];
    int row0 = blockIdx.x * 8;
    {
        int r = t >> 5, c = t & 31;
        int row = row0 + r;
        hs[r][c] = (row < n) ? hin[(size_t)row * HID + c] : 0.f;
    }
    __syncthreads();
    int r = t >> 5, col = t & 31;
    int row = row0 + r;
    if (row < n) {
        float s = 0.f;
        #pragma unroll
        for (int k = 0; k < HID; ++k) s += hs[r][k] * Ws[k * HID + col];
        h2[(size_t)row * HID + col]  = s;
        h2h[(size_t)row * HID + col] = __float2half(s);
    }
}

extern "C" void kernel_launch(void* const* d_in, const int* in_sizes, int n_in,
                              void* d_out, int out_size, void* d_ws, size_t ws_size,
                              hipStream_t stream) {
    const float* x  = (const float*)d_in[0];
    const int*   ei = (const int*)d_in[1];
    const float* W1 = (const float*)d_in[2];
    const float* b1 = (const float*)d_in[3];
    const float* W2 = (const float*)d_in[4];
    const float* b2 = (const float*)d_in[5];
    float* out = (float*)d_out;

    int n = in_sizes[0] / FIN;      // 100000
    int E = in_sizes[1] / 2;        // 3200000
    const int* src = ei;
    const int* dst = ei + E;

    int nb = (n + BNODES - 1) / BNODES;          // 1563 buckets

    size_t fixed = 3 * (size_t)n * 4             // dinv, rowbeg, rowcnt
                 + (size_t)nb * 4                // fill
                 + 2 * (size_t)n * HID * 4       // h0 fp32, acc fp32
                 + (size_t)n * HID * 2           // h fp16
                 + 16384;
    int cap = CAPMAX;
    if (ws_size) {
        size_t avail = (ws_size > fixed) ? (ws_size - fixed) : 0;
        int maxcap = (int)(avail / ((size_t)nb * 8));
        if (maxcap < cap) cap = maxcap & ~31;    // still >= ~2300 expected worst-case fill
    }

    char* ws = (char*)d_ws;
    size_t off = 0;
    auto alloc = [&](size_t bytes) { char* p = ws + off; off += (bytes + 255) & ~(size_t)255; return p; };
    int*    entries = (int*)alloc((size_t)nb * cap * 4);
    float*  wts     = (float*)alloc((size_t)nb * cap * 4);
    int*    fill    = (int*)alloc((size_t)nb * 4);
    float*  dinv    = (float*)alloc((size_t)n * 4);
    int*    rowbeg  = (int*)alloc((size_t)n * 4);
    int*    rowcnt  = (int*)alloc((size_t)n * 4);
    float*  h0      = (float*)alloc((size_t)n * HID * 4);
    float*  acc     = (float*)alloc((size_t)n * HID * 4);
    __half* hh      = (__half*)alloc((size_t)n * HID * 2);
    float*  h2      = h0;   // h0 fp32 dead after gather1; reuse for layer-2 features

    // ---- preprocessing: bucket sort -> node-sorted CSR + dinv + weights ----
    hipMemsetAsync(fill, 0, (size_t)nb * 4, stream);
    {
        int nblocks = (E + P2_CHUNK - 1) / P2_CHUNK;
        bucket_scatter_kernel<<<nblocks, 256, nb * 4, stream>>>(src, dst, fill, entries, E, nb, cap);
    }
    bucket_sortdinv_kernel<<<nb, 256, 0, stream>>>(entries, fill, dinv, rowbeg, rowcnt, n, cap);
    wfill_kernel<<<nb, 256, 0, stream>>>(entries, fill, dinv, wts, n, cap);

    // ---- layer 1 ----
    gemm1_kernel<<<(n + 7) / 8, 256, 0, stream>>>(x, W1, h0, hh, n);
    gather_kernel<<<(n + 7) / 8, 256, 0, stream>>>(entries, wts, rowbeg, rowcnt, dinv, h0, hh, b1, acc, n, 1);

    // ---- layer 2 ----
    gemm2_kernel<<<(n + 7) / 8, 256, 0, stream>>>(acc, W2, h2, hh, n);
    gather_kernel<<<(n + 7) / 8, 256, 0, stream>>>(entries, wts, rowbeg, rowcnt, dinv, h2, hh, b2, out, n, 1);
}

// Round 6
// 323.705 us; speedup vs baseline: 4.8673x; 1.3569x over previous
//
#include <hip/hip_runtime.h>
#include <hip/hip_fp16.h>

#define FIN 128
#define HID 32
#define BSHIFT 6                 // 64 nodes per bucket
#define BNODES 64
#define P2_CHUNK 4096            // edges per block in bucket-scatter kernel (782 blocks)
#define CAPMAX 2560              // max entries per bucket (mean 2047, max ~2200)

// ---------------- P2: bucket-scatter edges ----------------
// entries[b*cap + i] = src | (dlocal << 25), grouped by coarse bucket b = dst>>6.

__global__ __launch_bounds__(256) void bucket_scatter_kernel(const int* __restrict__ src,
                                                             const int* __restrict__ dst,
                                                             int* __restrict__ fill,
                                                             int* __restrict__ entries,
                                                             int E, int nb, int cap) {
    extern __shared__ int hist[];   // nb ints
    int t = threadIdx.x;
    for (int i = t; i < nb; i += 256) hist[i] = 0;
    __syncthreads();
    int beg = blockIdx.x * P2_CHUNK;
    int end = min(beg + P2_CHUNK, E);
    for (int i = beg + t; i < end; i += 256) {
        int b = ((unsigned)dst[i]) >> BSHIFT;
        atomicAdd(&hist[b], 1);
    }
    __syncthreads();
    // claim contiguous ranges: ONE aggregated global atomic per (block,bucket)
    for (int b = t; b < nb; b += 256) {
        int c = hist[b];
        hist[b] = (c > 0) ? atomicAdd(&fill[b], c) : 0;
    }
    __syncthreads();
    for (int i = beg + t; i < end; i += 256) {
        int d = dst[i];
        int b = ((unsigned)d) >> BSHIFT;
        int pos = atomicAdd(&hist[b], 1);
        if (pos < cap)
            entries[(size_t)b * cap + pos] = src[i] | ((d & (BNODES - 1)) << 25);
    }
}

// ---------------- counting sort within each bucket (LDS) + dinv + rowptr ----------------

__global__ __launch_bounds__(256) void bucket_sortdinv_kernel(int* __restrict__ entries,
                                                              const int* __restrict__ fill,
                                                              float* __restrict__ dinv,
                                                              int* __restrict__ rowbeg,
                                                              int* __restrict__ rowcnt,
                                                              int n, int cap) {
    __shared__ int raw[CAPMAX];
    __shared__ int srt[CAPMAX];
    __shared__ int hist[BNODES];
    __shared__ int pref[BNODES];
    __shared__ int cursor[BNODES];
    int b = blockIdx.x, t = threadIdx.x;
    int base = b * cap;
    int cnt = min(fill[b], cap);
    int* ep = entries + (size_t)base;
    if (t < BNODES) hist[t] = 0;
    __syncthreads();
    for (int i = t; i < cnt; i += 256) {
        int e = ep[i];
        raw[i] = e;
        atomicAdd(&hist[((unsigned)e) >> 25], 1);
    }
    __syncthreads();
    if (t == 0) {                      // tiny serial scan over 64 counters
        int run = 0;
        for (int i = 0; i < BNODES; ++i) { pref[i] = run; run += hist[i]; }
    }
    __syncthreads();
    if (t < BNODES) cursor[t] = pref[t];
    __syncthreads();
    for (int i = t; i < cnt; i += 256) {
        int e = raw[i];
        int dl = ((unsigned)e) >> 25;
        int p = atomicAdd(&cursor[dl], 1);
        srt[p] = e;
    }
    __syncthreads();
    for (int i = t; i < cnt; i += 256) ep[i] = srt[i];  // coalesced write-back, node-sorted
    int node = b * BNODES + t;
    if (t < BNODES && node < n) {
        int deg = hist[t];
        dinv[node]   = rsqrtf((float)deg + 1.0f);   // +1 = self-loop
        rowbeg[node] = base + pref[t];
        rowcnt[node] = deg;
    }
}

// ---------------- GEMM1: h0 = x @ W1; h16 = h0 * dinv (pre-scaled fp16 copy) ----------------

__global__ __launch_bounds__(256) void gemm1_kernel(const float* __restrict__ x,
                                                    const float* __restrict__ W,
                                                    const float* __restrict__ dinv,
                                                    float* __restrict__ h0,
                                                    __half* __restrict__ h0h, int n) {
    __shared__ float Ws[FIN * HID];   // 16 KB
    __shared__ float xs[8][FIN];      // 4 KB
    int t = threadIdx.x;
    for (int i = t; i < FIN * HID; i += 256) Ws[i] = W[i];
    int row0 = blockIdx.x * 8;
    {
        int r  = t >> 5;
        int c4 = (t & 31) * 4;
        int row = row0 + r;
        float4 v = (row < n) ? *(const float4*)&x[(size_t)row * FIN + c4]
                             : make_float4(0.f, 0.f, 0.f, 0.f);
        *(float4*)&xs[r][c4] = v;
    }
    __syncthreads();
    int r = t >> 5, col = t & 31;
    int row = row0 + r;
    if (row < n) {
        float acc = 0.f;
        #pragma unroll 16
        for (int k = 0; k < FIN; ++k) acc += xs[r][k] * Ws[k * HID + col];
        h0[(size_t)row * HID + col]  = acc;
        h0h[(size_t)row * HID + col] = __float2half(acc * dinv[row]);
    } else {
        h0h[(size_t)row * HID + col] = __float2half(0.f);  // zero sentinel rows >= n
    }
}

// ---------------- gather: out[i] = relu( b + h32[i]*di^2 + di * sum_e h16[src] ) ----------------

__global__ __launch_bounds__(256) void gather_kernel(const int* __restrict__ entries,
                                                     const int* __restrict__ rowbeg,
                                                     const int* __restrict__ rowcnt,
                                                     const float* __restrict__ dinv,
                                                     const float* __restrict__ h32,
                                                     const __half* __restrict__ h16,
                                                     const float* __restrict__ bias,
                                                     float* __restrict__ out, int n, int sent) {
    int g = threadIdx.x >> 5, f = threadIdx.x & 31;
    int i = blockIdx.x * 8 + g;
    if (i >= n) return;
    float di = dinv[i];
    float s = 0.f;
    int beg = rowbeg[i], cnt = rowcnt[i];
    for (int base = 0; base < cnt; base += 32) {
        int idx = beg + base + f;
        int sv = ((base + f) < cnt) ? entries[idx] : sent;  // sentinel = zero row n
        #pragma unroll
        for (int j0 = 0; j0 < 32; j0 += 8) {
            float hv[8];
            #pragma unroll
            for (int j = 0; j < 8; ++j) {
                int e = __shfl(sv, j0 + j, 32);
                hv[j] = __half2float(h16[(size_t)(e & 0x1FFFFFF) * HID + f]);
            }
            #pragma unroll
            for (int j = 0; j < 8; ++j) s += hv[j];
        }
    }
    float r = bias[f] + h32[(size_t)i * HID + f] * di * di + di * s;
    out[(size_t)i * HID + f] = fmaxf(r, 0.f);
}

// ---------------- GEMM2: h2 = hin @ W2; h16 = h2 * dinv ----------------

__global__ __launch_bounds__(256) void gemm2_kernel(const float* __restrict__ hin,
                                                    const float* __restrict__ W,
                                                    const float* __restrict__ dinv,
                                                    float* __restrict__ h2,
                                                    __half* __restrict__ h2h, int n) {
    __shared__ float Ws[HID * HID];
    __shared__ float hs[8][HID];
    int t = threadIdx.x;
    for (int i = t; i < HID * HID; i += 256) Ws[i] = W[i];
    int row0 = blockIdx.x * 8;
    {
        int r = t >> 5, c = t & 31;
        int row = row0 + r;
        hs[r][c] = (row < n) ? hin[(size_t)row * HID + c] : 0.f;
    }
    __syncthreads();
    int r = t >> 5, col = t & 31;
    int row = row0 + r;
    if (row < n) {
        float s = 0.f;
        #pragma unroll
        for (int k = 0; k < HID; ++k) s += hs[r][k] * Ws[k * HID + col];
        h2[(size_t)row * HID + col]  = s;
        h2h[(size_t)row * HID + col] = __float2half(s * dinv[row]);
    } else {
        h2h[(size_t)row * HID + col] = __float2half(0.f);
    }
}

extern "C" void kernel_launch(void* const* d_in, const int* in_sizes, int n_in,
                              void* d_out, int out_size, void* d_ws, size_t ws_size,
                              hipStream_t stream) {
    const float* x  = (const float*)d_in[0];
    const int*   ei = (const int*)d_in[1];
    const float* W1 = (const float*)d_in[2];
    const float* b1 = (const float*)d_in[3];
    const float* W2 = (const float*)d_in[4];
    const float* b2 = (const float*)d_in[5];
    float* out = (float*)d_out;

    int n = in_sizes[0] / FIN;      // 100000
    int E = in_sizes[1] / 2;        // 3200000
    const int* src = ei;
    const int* dst = ei + E;

    int nb = (n + BNODES - 1) / BNODES;          // 1563 buckets
    int ngrid = (n + 8) / 8;                     // covers row n (sentinel) too
    int npad = ngrid * 8;                        // h16 rows allocated

    size_t fixed = 3 * (size_t)n * 4             // dinv, rowbeg, rowcnt
                 + (size_t)nb * 4                // fill
                 + 2 * (size_t)n * HID * 4       // h0 fp32, acc fp32
                 + (size_t)npad * HID * 2        // h fp16 (+sentinel rows)
                 + 16384;
    int cap = CAPMAX;
    if (ws_size) {
        size_t avail = (ws_size > fixed) ? (ws_size - fixed) : 0;
        int maxcap = (int)(avail / ((size_t)nb * 4));
        if (maxcap < cap) cap = maxcap & ~31;
    }

    char* ws = (char*)d_ws;
    size_t off = 0;
    auto alloc = [&](size_t bytes) { char* p = ws + off; off += (bytes + 255) & ~(size_t)255; return p; };
    int*    entries = (int*)alloc((size_t)nb * cap * 4);
    int*    fill    = (int*)alloc((size_t)nb * 4);
    float*  dinv    = (float*)alloc((size_t)n * 4);
    int*    rowbeg  = (int*)alloc((size_t)n * 4);
    int*    rowcnt  = (int*)alloc((size_t)n * 4);
    float*  h0      = (float*)alloc((size_t)n * HID * 4);
    float*  acc     = (float*)alloc((size_t)n * HID * 4);
    __half* hh      = (__half*)alloc((size_t)npad * HID * 2);
    float*  h2      = h0;   // h0 fp32 dead after gather1; reuse for layer-2 features

    // ---- preprocessing: bucket sort -> node-sorted CSR + dinv ----
    hipMemsetAsync(fill, 0, (size_t)nb * 4, stream);
    {
        int nblocks = (E + P2_CHUNK - 1) / P2_CHUNK;
        bucket_scatter_kernel<<<nblocks, 256, nb * 4, stream>>>(src, dst, fill, entries, E, nb, cap);
    }
    bucket_sortdinv_kernel<<<nb, 256, 0, stream>>>(entries, fill, dinv, rowbeg, rowcnt, n, cap);

    // ---- layer 1 ----
    gemm1_kernel<<<ngrid, 256, 0, stream>>>(x, W1, dinv, h0, hh, n);
    gather_kernel<<<(n + 7) / 8, 256, 0, stream>>>(entries, rowbeg, rowcnt, dinv, h0, hh, b1, acc, n, n);

    // ---- layer 2 ----
    gemm2_kernel<<<ngrid, 256, 0, stream>>>(acc, W2, dinv, h2, hh, n);
    gather_kernel<<<(n + 7) / 8, 256, 0, stream>>>(entries, rowbeg, rowcnt, dinv, h2, hh, b2, out, n, n);
}